// Round 12
// baseline (767.088 us; speedup 1.0000x reference)
//
#include <hip/hip_runtime.h>
#include <hip/hip_fp16.h>

#define NN 100000
#define EE 1200000
#define DD 64
#define CC 40
#define KK 16
#define BSZ 196                          // nodes per sort bucket
#define NBK 512                          // buckets (512*196 = 100352 >= NN)
#define TCAP 3072                        // tmp capacity per bucket (mean 2352, ~15 sigma)
#define EPB 4096                         // edges per phase-A block
#define ABLK ((EE + EPB - 1) / EPB)      // 293
#define GBLK32 ((NN + 31) / 32)          // 3125 spmm blocks per phase
// x-buffer plane offsets (float4 units): P0 dims0-15, P1 dims16-31, P2 dims32-39
#define P1OFF (NN * 2)
#define P2OFF (NN * 4)

typedef float vf4 __attribute__((ext_vector_type(4)));

struct __align__(8) ERec { int c; float w; };

// ---------- cursor init ----------
__global__ __launch_bounds__(512) void curinit_kernel(int* __restrict__ cursor) {
    int b = threadIdx.x;
    if (b < NBK) cursor[b] = b * TCAP;
}

// ---------- sort phase A: LDS-bin 4096 edges into 512 buckets ----------
__global__ __launch_bounds__(256) void sortA_kernel(const int* __restrict__ src,
                                                    const int* __restrict__ dst,
                                                    int* __restrict__ cursor,
                                                    int2* __restrict__ tmp) {
    __shared__ int2 stg[EPB];                 // 32KB
    __shared__ int hist[NBK], loff[NBK], lcur[NBK], gbase[NBK];  // 8KB
    int t = threadIdx.x;
    long e0 = (long)blockIdx.x * EPB;
    int n = (int)((EE - e0 < EPB) ? (EE - e0) : EPB);
    for (int j = t; j < NBK; j += 256) hist[j] = 0;
    __syncthreads();
    int d[16], sx[16];
#pragma unroll
    for (int j = 0; j < 16; ++j) {
        int i = t + j * 256;
        if (i < n) {
            d[j] = dst[e0 + i];
            sx[j] = src[e0 + i];
            atomicAdd(&hist[d[j] / BSZ], 1);
        } else d[j] = -1;
    }
    __syncthreads();
    int c0 = hist[2 * t], c1 = hist[2 * t + 1];
    int s2 = c0 + c1;
    __syncthreads();
    loff[t] = s2;
    __syncthreads();
    for (int off = 1; off < 256; off <<= 1) {
        int u = (t >= off) ? loff[t - off] : 0;
        __syncthreads();
        loff[t] += u;
        __syncthreads();
    }
    int excl = loff[t] - s2;
    __syncthreads();
    loff[2 * t] = excl;          loff[2 * t + 1] = excl + c0;
    lcur[2 * t] = excl;          lcur[2 * t + 1] = excl + c0;
    gbase[2 * t]     = atomicAdd(&cursor[2 * t], c0);
    gbase[2 * t + 1] = atomicAdd(&cursor[2 * t + 1], c1);
    __syncthreads();
#pragma unroll
    for (int j = 0; j < 16; ++j) {
        if (d[j] >= 0) {
            int b = d[j] / BSZ;
            int p = atomicAdd(&lcur[b], 1);
            stg[p] = make_int2(d[j], sx[j]);
        }
    }
    __syncthreads();
    for (int i = t; i < n; i += 256) {
        int2 r = stg[i];
        int b = r.x / BSZ;
        int pos = gbase[b] + (i - loff[b]);
        if (pos < (b + 1) * TCAP) tmp[pos] = r;  // overflow guard (never hit)
    }
}

// ---------- bucket-base scan ----------
__global__ __launch_bounds__(512) void bscan_kernel(const int* __restrict__ cursor,
                                                    int* __restrict__ bbase,
                                                    int* __restrict__ row_ptr) {
    __shared__ int sm[512];
    int t = threadIdx.x;
    int v = (t < NBK) ? (cursor[t] - t * TCAP) : 0;
    sm[t] = v;
    __syncthreads();
    for (int off = 1; off < 512; off <<= 1) {
        int u = (t >= off) ? sm[t - off] : 0;
        __syncthreads();
        sm[t] += u;
        __syncthreads();
    }
    if (t < NBK) bbase[t] = sm[t] - v;
    if (t == 511) row_ptr[NN] = sm[511];  // == EE
}

// ---------- sort phase B: counting sort within bucket ----------
__global__ __launch_bounds__(256) void sortB_kernel(const int2* __restrict__ tmp,
                                                    const int* __restrict__ cursor,
                                                    const int* __restrict__ bbase,
                                                    float* __restrict__ dinv,
                                                    int* __restrict__ row_ptr,
                                                    int2* __restrict__ er2) {
    __shared__ int2 se[TCAP];     // 24KB
    __shared__ int2 so[TCAP];     // 24KB
    __shared__ int hist[256], lcur[256];
    int b = blockIdx.x;
    int n0 = b * BSZ;
    if (n0 >= NN) return;
    int n1 = n0 + BSZ; if (n1 > NN) n1 = NN;
    int nb = n1 - n0;
    int t = threadIdx.x;
    int cnt = cursor[b] - b * TCAP;
    int base = bbase[b];
    hist[t] = 0;
    __syncthreads();
    for (int i = t; i < cnt; i += 256) {
        int2 r = tmp[b * TCAP + i];
        se[i] = r;
        atomicAdd(&hist[r.x - n0], 1);
    }
    __syncthreads();
    if (t < nb) dinv[n0 + t] = rsqrtf((float)(hist[t] + 1));  // +1 self-loop
    int v = hist[t];
    lcur[t] = v;
    __syncthreads();
    for (int off = 1; off < 256; off <<= 1) {
        int u = (t >= off) ? lcur[t - off] : 0;
        __syncthreads();
        lcur[t] += u;
        __syncthreads();
    }
    int excl = lcur[t] - v;
    __syncthreads();
    lcur[t] = excl;
    if (t < nb) row_ptr[n0 + t] = base + excl;
    __syncthreads();
    for (int i = t; i < cnt; i += 256) {
        int2 r = se[i];
        int ln = r.x - n0;
        int pos = atomicAdd(&lcur[ln], 1);
        so[pos] = make_int2(r.y, r.x);  // (src, dst)
    }
    __syncthreads();
    for (int i = t; i < cnt; i += 256) er2[base + i] = so[i];  // coalesced
}

// ---------- weight fill: packed 4B records src(17b) | fp16-w-sans-sign(15b) ----------
__global__ __launch_bounds__(256) void wfill_kernel(const int2* __restrict__ er2,
                                                    const float* __restrict__ dinv,
                                                    unsigned int* __restrict__ er4) {
    int i = blockIdx.x * 256 + threadIdx.x;
    if (i >= EE) return;
    int2 r = er2[i];
    float w = dinv[r.y] * dinv[r.x];
    unsigned short hb = __half_as_ushort(__float2half_rn(w)) & 0x7FFF;
    er4[i] = (unsigned int)r.x | ((unsigned int)hb << 17);
}

// ---------- projection: y0 = feat @ W^T (LDS-tiled), 3-plane fp16 layout ----------
__global__ __launch_bounds__(256) void proj_kernel(const float4* __restrict__ feat4,
                                                   const float* __restrict__ W,
                                                   float4* __restrict__ y0) {
    __shared__ float smW[CC * 68];   // 10.9KB
    __shared__ float smF[64 * 68];   // 17.4KB
    __shared__ float smO[64 * 42];   // 10.8KB
    int t = threadIdx.x;
    for (int j = t; j < CC * 16; j += 256) {
        int c = j >> 4, q = j & 15;
        *(float4*)(smW + c * 68 + q * 4) = ((const float4*)W)[j];
    }
    int n0 = blockIdx.x * 64;
    for (int j = t; j < 64 * 16; j += 256) {
        int r = j >> 4, q = j & 15;
        if (n0 + r < NN)
            *(float4*)(smF + r * 68 + q * 4) = feat4[(size_t)(n0 + r) * 16 + q];
    }
    __syncthreads();
    int ln = t >> 2, c0 = (t & 3) * 10;
    int node = n0 + ln;
    float acc[10];
#pragma unroll
    for (int c = 0; c < 10; ++c) acc[c] = 0.f;
    if (node < NN) {
#pragma unroll
        for (int db = 0; db < 16; ++db) {
            float4 fv = *(const float4*)(smF + ln * 68 + db * 4);
#pragma unroll
            for (int c = 0; c < 10; ++c) {
                float4 wv = *(const float4*)(smW + (c0 + c) * 68 + db * 4);
                acc[c] = fmaf(fv.x, wv.x, acc[c]);
                acc[c] = fmaf(fv.y, wv.y, acc[c]);
                acc[c] = fmaf(fv.z, wv.z, acc[c]);
                acc[c] = fmaf(fv.w, wv.w, acc[c]);
            }
        }
    }
#pragma unroll
    for (int c = 0; c < 10; ++c) smO[ln * 42 + c0 + c] = acc[c];
    __syncthreads();
    for (int j = t; j < 64 * 5; j += 256) {
        int r = j / 5, q = j - r * 5;
        int i = n0 + r;
        if (i < NN) {
            const float* s = smO + r * 42 + q * 8;
            float4 ov;
            __half2* op = (__half2*)&ov;
            op[0] = __floats2half2_rn(s[0], s[1]);
            op[1] = __floats2half2_rn(s[2], s[3]);
            op[2] = __floats2half2_rn(s[4], s[5]);
            op[3] = __floats2half2_rn(s[6], s[7]);
            size_t idx = (q < 2) ? ((size_t)i * 2 + q)
                       : (q < 4) ? ((size_t)P1OFF + i * 2 + (q - 2))
                                 : ((size_t)P2OFF + i);
            y0[idx] = ov;
        }
    }
}

// decode float4-of-8-halves into 8 floats
#define DEC8(V, F0, F1, F2, F3)                                             \
    const __half2* hp_##F0 = (const __half2*)&(V);                          \
    float2 F0 = __half22float2(hp_##F0[0]), F1 = __half22float2(hp_##F0[1]);\
    float2 F2 = __half22float2(hp_##F0[2]), F3 = __half22float2(hp_##F0[3]);

#define ACC8(WW, V)                                                         \
    {                                                                       \
        DEC8(V, f0, f1, f2, f3)                                             \
        a0 = fmaf((WW), f0.x, a0); a1 = fmaf((WW), f0.y, a1);               \
        a2 = fmaf((WW), f1.x, a2); a3 = fmaf((WW), f1.y, a3);               \
        a4 = fmaf((WW), f2.x, a4); a5 = fmaf((WW), f2.y, a5);               \
        a6 = fmaf((WW), f3.x, a6); a7 = fmaf((WW), f3.y, a7);               \
    }

#define WDEC(Q) __half2float(__ushort_as_half((unsigned short)((Q) >> 17)))

// edge loop: unroll x8, then x4, then singles; er via nt loads
#define EDGE_LOOP                                                           \
    int e = beg;                                                            \
    int e8 = beg + ((end - beg) & ~7);                                      \
    for (; e < e8; e += 8) {                                                \
        unsigned q0 = __builtin_nontemporal_load(er + e);                   \
        unsigned q1 = __builtin_nontemporal_load(er + e + 1);               \
        unsigned q2 = __builtin_nontemporal_load(er + e + 2);               \
        unsigned q3 = __builtin_nontemporal_load(er + e + 3);               \
        unsigned q4 = __builtin_nontemporal_load(er + e + 4);               \
        unsigned q5 = __builtin_nontemporal_load(er + e + 5);               \
        unsigned q6 = __builtin_nontemporal_load(er + e + 6);               \
        unsigned q7 = __builtin_nontemporal_load(er + e + 7);               \
        float4 v0 = xp[(q0 & 0x1FFFFu) * st + li];                          \
        float4 v1 = xp[(q1 & 0x1FFFFu) * st + li];                          \
        float4 v2 = xp[(q2 & 0x1FFFFu) * st + li];                          \
        float4 v3 = xp[(q3 & 0x1FFFFu) * st + li];                          \
        float4 v4 = xp[(q4 & 0x1FFFFu) * st + li];                          \
        float4 v5 = xp[(q5 & 0x1FFFFu) * st + li];                          \
        float4 v6 = xp[(q6 & 0x1FFFFu) * st + li];                          \
        float4 v7 = xp[(q7 & 0x1FFFFu) * st + li];                          \
        ACC8(WDEC(q0), v0); ACC8(WDEC(q1), v1);                             \
        ACC8(WDEC(q2), v2); ACC8(WDEC(q3), v3);                             \
        ACC8(WDEC(q4), v4); ACC8(WDEC(q5), v5);                             \
        ACC8(WDEC(q6), v6); ACC8(WDEC(q7), v7);                             \
    }                                                                       \
    int e4 = e + ((end - e) & ~3);                                          \
    for (; e < e4; e += 4) {                                                \
        unsigned q0 = __builtin_nontemporal_load(er + e);                   \
        unsigned q1 = __builtin_nontemporal_load(er + e + 1);               \
        unsigned q2 = __builtin_nontemporal_load(er + e + 2);               \
        unsigned q3 = __builtin_nontemporal_load(er + e + 3);               \
        float4 v0 = xp[(q0 & 0x1FFFFu) * st + li];                          \
        float4 v1 = xp[(q1 & 0x1FFFFu) * st + li];                          \
        float4 v2 = xp[(q2 & 0x1FFFFu) * st + li];                          \
        float4 v3 = xp[(q3 & 0x1FFFFu) * st + li];                          \
        ACC8(WDEC(q0), v0); ACC8(WDEC(q1), v1);                             \
        ACC8(WDEC(q2), v2); ACC8(WDEC(q3), v3);                             \
    }                                                                       \
    for (; e < end; ++e) {                                                  \
        unsigned q = __builtin_nontemporal_load(er + e);                    \
        float4 v = xp[(q & 0x1FFFFu) * st + li];                            \
        ACC8(WDEC(q), v);                                                   \
    }

// phase -> (g, li, st, plane base ptr). Phase 0/1: 32 nodes/wave, 2 lanes each.
// Phase 2: 32 nodes/wave, 1 lane each (lanes 32-63 idle).
#define PHASE_SETUP(XBUF)                                                   \
    int ph = blockIdx.y;                                                    \
    int lane = threadIdx.x;                                                 \
    int g, li, st;                                                          \
    const float4* xp;                                                       \
    if (ph < 2) {                                                           \
        g = blockIdx.x * 32 + (lane >> 1);                                  \
        li = lane & 1; st = 2;                                              \
        xp = (XBUF) + (ph ? P1OFF : 0);                                     \
    } else {                                                                \
        if (lane >= 32) return;                                             \
        g = blockIdx.x * 32 + lane;                                         \
        li = 0; st = 1;                                                     \
        xp = (XBUF) + P2OFF;                                                \
    }                                                                       \
    if (g >= NN) return;

// ---------- SpMM propagate: x_out = A_hat * x, 3-phase (dims 0-15/16-31/32-39)
// Phases separate temporally (x-fastest dispatch) so the active 3.2MB/1.6MB
// gather plane stays L2-resident. nt stores keep x_out from evicting it.
__global__ __launch_bounds__(64) void spmm_prop(
    const float4* __restrict__ x, float4* __restrict__ x_out,
    const int* __restrict__ row_ptr, const unsigned int* __restrict__ er,
    const float* __restrict__ dinv) {
    PHASE_SETUP(x)
    int beg = row_ptr[g], end = row_ptr[g + 1];
    float di = dinv[g];
    float w0 = di * di;
    int base = g * st + li;
    float4 sv = xp[base];
    float a0, a1, a2, a3, a4, a5, a6, a7;
    {
        DEC8(sv, f0, f1, f2, f3)
        a0 = w0 * f0.x; a1 = w0 * f0.y; a2 = w0 * f1.x; a3 = w0 * f1.y;
        a4 = w0 * f2.x; a5 = w0 * f2.y; a6 = w0 * f3.x; a7 = w0 * f3.y;
    }
    EDGE_LOOP
    float4 ov;
    __half2* op = (__half2*)&ov;
    op[0] = __floats2half2_rn(a0, a1);
    op[1] = __floats2half2_rn(a2, a3);
    op[2] = __floats2half2_rn(a4, a5);
    op[3] = __floats2half2_rn(a6, a7);
    float4* dst4 = x_out + (xp - x) + base;
    __builtin_nontemporal_store(*(const vf4*)&ov, (vf4*)dst4);
}

// ---------- final: acc = A*x15 (=x16); out = C16*x16 + C15*x15 + C14*x14
//            + C13*x13 + FC*y0 + bias   (k<=12 terms <= ~3e-6, dropped)
__global__ __launch_bounds__(64) void spmm_final(
    const float4* __restrict__ x,     // x15 (gather source)
    const float4* __restrict__ x13p,
    const float4* __restrict__ x14p,
    const float4* __restrict__ y0,
    const float* __restrict__ bias,
    const int* __restrict__ row_ptr, const unsigned int* __restrict__ er,
    const float* __restrict__ dinv, float* __restrict__ outp) {
    PHASE_SETUP(x)
    int beg = row_ptr[g], end = row_ptr[g + 1];
    float di = dinv[g];
    float w0 = di * di;
    int base = g * st + li;
    long poff = xp - x;  // plane offset in float4 units
    float4 sv = xp[base];
    float s0, s1, s2, s3, s4, s5, s6, s7;
    float a0, a1, a2, a3, a4, a5, a6, a7;
    {
        DEC8(sv, f0, f1, f2, f3)
        s0 = f0.x; s1 = f0.y; s2 = f1.x; s3 = f1.y;
        s4 = f2.x; s5 = f2.y; s6 = f3.x; s7 = f3.y;
        a0 = w0 * s0; a1 = w0 * s1; a2 = w0 * s2; a3 = w0 * s3;
        a4 = w0 * s4; a5 = w0 * s5; a6 = w0 * s6; a7 = w0 * s7;
    }
    EDGE_LOOP
    const float C16 = 0.95f / 16.0f;
    const float C15 = 0.95f / 256.0f;
    const float C14 = 0.95f / 4096.0f;
    const float C13 = 0.95f / 65536.0f;
    const float FC  = 0.05f / 15.0f;
    float o0 = C16 * a0 + C15 * s0, o1 = C16 * a1 + C15 * s1;
    float o2 = C16 * a2 + C15 * s2, o3 = C16 * a3 + C15 * s3;
    float o4 = C16 * a4 + C15 * s4, o5 = C16 * a5 + C15 * s5;
    float o6 = C16 * a6 + C15 * s6, o7 = C16 * a7 + C15 * s7;
#define ADD8(P, CF)                                                         \
    {                                                                       \
        float4 v = (P)[poff + base];                                        \
        DEC8(v, f0, f1, f2, f3)                                             \
        o0 = fmaf((CF), f0.x, o0); o1 = fmaf((CF), f0.y, o1);               \
        o2 = fmaf((CF), f1.x, o2); o3 = fmaf((CF), f1.y, o3);               \
        o4 = fmaf((CF), f2.x, o4); o5 = fmaf((CF), f2.y, o5);               \
        o6 = fmaf((CF), f3.x, o6); o7 = fmaf((CF), f3.y, o7);               \
    }
    ADD8(x14p, C14)
    ADD8(x13p, C13)
    ADD8(y0, FC)
#undef ADD8
    int d0 = (ph < 2) ? (ph * 16 + li * 8) : 32;
    const float4* b4 = (const float4*)(bias + d0);
    float4 bb0 = b4[0], bb1 = b4[1];
    float4 w0v = make_float4(o0 + bb0.x, o1 + bb0.y, o2 + bb0.z, o3 + bb0.w);
    float4 w1v = make_float4(o4 + bb1.x, o5 + bb1.y, o6 + bb1.z, o7 + bb1.w);
    float4* op = (float4*)(outp + (size_t)g * CC + d0);
    op[0] = w0v; op[1] = w1v;
}

extern "C" void kernel_launch(void* const* d_in, const int* in_sizes, int n_in,
                              void* d_out, int out_size, void* d_ws, size_t ws_size,
                              hipStream_t stream) {
    const float* feat = (const float*)d_in[0];
    const float* W    = (const float*)d_in[1];
    const float* b    = (const float*)d_in[2];
    const int*   src  = (const int*)d_in[3];
    const int*   dst  = (const int*)d_in[4];
    float* out = (float*)d_out;

    char* p = (char*)d_ws;
    auto alloc = [&](size_t bytes) {
        char* r = p;
        p += (bytes + 255) & ~(size_t)255;
        return r;
    };
    float*        dinv    = (float*)alloc((size_t)NN * sizeof(float));
    int*          row_ptr = (int*)alloc((size_t)(NN + 1) * sizeof(int));
    int*          cursor  = (int*)alloc((size_t)NBK * sizeof(int));
    int*          bbase   = (int*)alloc((size_t)NBK * sizeof(int));
    int2*         tmp     = (int2*)alloc((size_t)NBK * TCAP * sizeof(int2)); // 12.6MB
    int2*         er2     = (int2*)alloc((size_t)EE * sizeof(int2));         // 9.6MB
    unsigned int* er4     = (unsigned int*)alloc((size_t)EE * sizeof(int));  // 4.8MB
    float4*       y0      = (float4*)alloc((size_t)NN * 5 * sizeof(float4)); // 8MB
    float4*       xa      = (float4*)alloc((size_t)NN * 5 * sizeof(float4)); // 8MB
    float4*       xb      = (float4*)alloc((size_t)NN * 5 * sizeof(float4)); // 8MB
    float4*       x13b    = (float4*)alloc((size_t)NN * 5 * sizeof(float4)); // 8MB
    float4*       x14b    = (float4*)alloc((size_t)NN * 5 * sizeof(float4)); // 8MB
    float4*       x15b    = (float4*)alloc((size_t)NN * 5 * sizeof(float4)); // 8MB

    curinit_kernel<<<1, 512, 0, stream>>>(cursor);
    sortA_kernel<<<ABLK, 256, 0, stream>>>(src, dst, cursor, tmp);
    bscan_kernel<<<1, 512, 0, stream>>>(cursor, bbase, row_ptr);
    sortB_kernel<<<NBK, 256, 0, stream>>>(tmp, cursor, bbase, dinv, row_ptr, er2);
    wfill_kernel<<<(EE + 255) / 256, 256, 0, stream>>>(er2, dinv, er4);
    proj_kernel<<<(NN + 63) / 64, 256, 0, stream>>>((const float4*)feat, W, y0);

    dim3 sgrid(GBLK32, 3);
    // j = 0..11: ping-pong xa/xb (x1..x12 don't feed the output)
    const float4* xs = y0;
    for (int j = 0; j < 12; ++j) {
        float4* xd = (j & 1) ? xb : xa;
        spmm_prop<<<sgrid, 64, 0, stream>>>(xs, xd, row_ptr, er4, dinv);
        xs = xd;
    }
    // x13, x14, x15 into preserved buffers
    spmm_prop<<<sgrid, 64, 0, stream>>>(xs, x13b, row_ptr, er4, dinv);
    spmm_prop<<<sgrid, 64, 0, stream>>>(x13b, x14b, row_ptr, er4, dinv);
    spmm_prop<<<sgrid, 64, 0, stream>>>(x14b, x15b, row_ptr, er4, dinv);
    // final: acc = A*x15 (=x16), combine x16,x15,x14,x13,y0,bias -> out
    spmm_final<<<sgrid, 64, 0, stream>>>(x15b, x13b, x14b, y0, b, row_ptr,
                                         er4, dinv, out);
}

// Round 13
// 629.953 us; speedup vs baseline: 1.2177x; 1.2177x over previous
//
#include <hip/hip_runtime.h>
#include <hip/hip_fp16.h>

#define NN 100000
#define EE 1200000
#define DD 64
#define CC 40
#define KK 16
#define BSZ 196                          // nodes per sort bucket
#define NBK 512                          // buckets (512*196 = 100352 >= NN)
#define TCAP 3072                        // tmp capacity per bucket (mean 2352, ~15 sigma)
#define EPB 4096                         // edges per phase-A block
#define ABLK ((EE + EPB - 1) / EPB)      // 293
#define PL1 (NN * 4)                     // float4-index offset of plane1 in an x buffer
#define GBLK24 ((NN + 23) / 24)          // 4167 two-wave spmm blocks

typedef float vf4 __attribute__((ext_vector_type(4)));

// ---------- cursor init ----------
__global__ __launch_bounds__(512) void curinit_kernel(int* __restrict__ cursor) {
    int b = threadIdx.x;
    if (b < NBK) cursor[b] = b * TCAP;
}

// ---------- sort phase A: LDS-bin 4096 edges into 512 buckets ----------
__global__ __launch_bounds__(256) void sortA_kernel(const int* __restrict__ src,
                                                    const int* __restrict__ dst,
                                                    int* __restrict__ cursor,
                                                    int2* __restrict__ tmp) {
    __shared__ int2 stg[EPB];                 // 32KB
    __shared__ int hist[NBK], loff[NBK], lcur[NBK], gbase[NBK];  // 8KB
    int t = threadIdx.x;
    long e0 = (long)blockIdx.x * EPB;
    int n = (int)((EE - e0 < EPB) ? (EE - e0) : EPB);
    for (int j = t; j < NBK; j += 256) hist[j] = 0;
    __syncthreads();
    int d[16], sx[16];
#pragma unroll
    for (int j = 0; j < 16; ++j) {
        int i = t + j * 256;
        if (i < n) {
            d[j] = dst[e0 + i];
            sx[j] = src[e0 + i];
            atomicAdd(&hist[d[j] / BSZ], 1);
        } else d[j] = -1;
    }
    __syncthreads();
    int c0 = hist[2 * t], c1 = hist[2 * t + 1];
    int s2 = c0 + c1;
    __syncthreads();
    loff[t] = s2;
    __syncthreads();
    for (int off = 1; off < 256; off <<= 1) {
        int u = (t >= off) ? loff[t - off] : 0;
        __syncthreads();
        loff[t] += u;
        __syncthreads();
    }
    int excl = loff[t] - s2;
    __syncthreads();
    loff[2 * t] = excl;          loff[2 * t + 1] = excl + c0;
    lcur[2 * t] = excl;          lcur[2 * t + 1] = excl + c0;
    gbase[2 * t]     = atomicAdd(&cursor[2 * t], c0);
    gbase[2 * t + 1] = atomicAdd(&cursor[2 * t + 1], c1);
    __syncthreads();
#pragma unroll
    for (int j = 0; j < 16; ++j) {
        if (d[j] >= 0) {
            int b = d[j] / BSZ;
            int p = atomicAdd(&lcur[b], 1);
            stg[p] = make_int2(d[j], sx[j]);
        }
    }
    __syncthreads();
    for (int i = t; i < n; i += 256) {
        int2 r = stg[i];
        int b = r.x / BSZ;
        int pos = gbase[b] + (i - loff[b]);
        if (pos < (b + 1) * TCAP) tmp[pos] = r;  // overflow guard (never hit)
    }
}

// ---------- bucket-base scan ----------
__global__ __launch_bounds__(512) void bscan_kernel(const int* __restrict__ cursor,
                                                    int* __restrict__ bbase,
                                                    int* __restrict__ row_ptr) {
    __shared__ int sm[512];
    int t = threadIdx.x;
    int v = (t < NBK) ? (cursor[t] - t * TCAP) : 0;
    sm[t] = v;
    __syncthreads();
    for (int off = 1; off < 512; off <<= 1) {
        int u = (t >= off) ? sm[t - off] : 0;
        __syncthreads();
        sm[t] += u;
        __syncthreads();
    }
    if (t < NBK) bbase[t] = sm[t] - v;
    if (t == 511) row_ptr[NN] = sm[511];  // == EE
}

// ---------- sort phase B: counting sort within bucket ----------
__global__ __launch_bounds__(256) void sortB_kernel(const int2* __restrict__ tmp,
                                                    const int* __restrict__ cursor,
                                                    const int* __restrict__ bbase,
                                                    float* __restrict__ dinv,
                                                    int* __restrict__ row_ptr,
                                                    int2* __restrict__ er2) {
    __shared__ int2 se[TCAP];     // 24KB
    __shared__ int2 so[TCAP];     // 24KB
    __shared__ int hist[256], lcur[256];
    int b = blockIdx.x;
    int n0 = b * BSZ;
    if (n0 >= NN) return;
    int n1 = n0 + BSZ; if (n1 > NN) n1 = NN;
    int nb = n1 - n0;
    int t = threadIdx.x;
    int cnt = cursor[b] - b * TCAP;
    int base = bbase[b];
    hist[t] = 0;
    __syncthreads();
    for (int i = t; i < cnt; i += 256) {
        int2 r = tmp[b * TCAP + i];
        se[i] = r;
        atomicAdd(&hist[r.x - n0], 1);
    }
    __syncthreads();
    if (t < nb) dinv[n0 + t] = rsqrtf((float)(hist[t] + 1));  // +1 self-loop
    int v = hist[t];
    lcur[t] = v;
    __syncthreads();
    for (int off = 1; off < 256; off <<= 1) {
        int u = (t >= off) ? lcur[t - off] : 0;
        __syncthreads();
        lcur[t] += u;
        __syncthreads();
    }
    int excl = lcur[t] - v;
    __syncthreads();
    lcur[t] = excl;
    if (t < nb) row_ptr[n0 + t] = base + excl;
    __syncthreads();
    for (int i = t; i < cnt; i += 256) {
        int2 r = se[i];
        int ln = r.x - n0;
        int pos = atomicAdd(&lcur[ln], 1);
        so[pos] = make_int2(r.y, r.x);  // (src, dst)
    }
    __syncthreads();
    for (int i = t; i < cnt; i += 256) er2[base + i] = so[i];  // coalesced
}

// ---------- weight fill: packed 4B records src(17b) | fp16-w-sans-sign(15b) ----------
// w = dinv[dst]*dinv[src] > 0 always, so the sign bit is droppable.
__global__ __launch_bounds__(256) void wfill_kernel(const int2* __restrict__ er2,
                                                    const float* __restrict__ dinv,
                                                    unsigned int* __restrict__ er4) {
    int i = blockIdx.x * 256 + threadIdx.x;
    if (i >= EE) return;
    int2 r = er2[i];
    float w = dinv[r.y] * dinv[r.x];
    unsigned short hb = __half_as_ushort(__float2half_rn(w)) & 0x7FFF;
    er4[i] = (unsigned int)r.x | ((unsigned int)hb << 17);
}

// ---------- projection: y0 = feat @ W^T (LDS-tiled), dual-plane fp16 ----------
__global__ __launch_bounds__(256) void proj_kernel(const float4* __restrict__ feat4,
                                                   const float* __restrict__ W,
                                                   float4* __restrict__ y0) {
    __shared__ float smW[CC * 68];   // 10.9KB
    __shared__ float smF[64 * 68];   // 17.4KB
    __shared__ float smO[64 * 42];   // 10.8KB
    int t = threadIdx.x;
    for (int j = t; j < CC * 16; j += 256) {
        int c = j >> 4, q = j & 15;
        *(float4*)(smW + c * 68 + q * 4) = ((const float4*)W)[j];
    }
    int n0 = blockIdx.x * 64;
    for (int j = t; j < 64 * 16; j += 256) {
        int r = j >> 4, q = j & 15;
        if (n0 + r < NN)
            *(float4*)(smF + r * 68 + q * 4) = feat4[(size_t)(n0 + r) * 16 + q];
    }
    __syncthreads();
    int ln = t >> 2, c0 = (t & 3) * 10;
    int node = n0 + ln;
    float acc[10];
#pragma unroll
    for (int c = 0; c < 10; ++c) acc[c] = 0.f;
    if (node < NN) {
#pragma unroll
        for (int db = 0; db < 16; ++db) {
            float4 fv = *(const float4*)(smF + ln * 68 + db * 4);
#pragma unroll
            for (int c = 0; c < 10; ++c) {
                float4 wv = *(const float4*)(smW + (c0 + c) * 68 + db * 4);
                acc[c] = fmaf(fv.x, wv.x, acc[c]);
                acc[c] = fmaf(fv.y, wv.y, acc[c]);
                acc[c] = fmaf(fv.z, wv.z, acc[c]);
                acc[c] = fmaf(fv.w, wv.w, acc[c]);
            }
        }
    }
#pragma unroll
    for (int c = 0; c < 10; ++c) smO[ln * 42 + c0 + c] = acc[c];
    __syncthreads();
    for (int j = t; j < 64 * 5; j += 256) {
        int r = j / 5, q = j - r * 5;
        int i = n0 + r;
        if (i < NN) {
            const float* s = smO + r * 42 + q * 8;
            float4 ov;
            __half2* op = (__half2*)&ov;
            op[0] = __floats2half2_rn(s[0], s[1]);
            op[1] = __floats2half2_rn(s[2], s[3]);
            op[2] = __floats2half2_rn(s[4], s[5]);
            op[3] = __floats2half2_rn(s[6], s[7]);
            y0[(q < 4) ? ((size_t)i * 4 + q) : (size_t)(PL1 + i)] = ov;
        }
    }
}

// decode float4-of-8-halves into 8 floats
#define DEC8(V, F0, F1, F2, F3)                                             \
    const __half2* hp_##F0 = (const __half2*)&(V);                          \
    float2 F0 = __half22float2(hp_##F0[0]), F1 = __half22float2(hp_##F0[1]);\
    float2 F2 = __half22float2(hp_##F0[2]), F3 = __half22float2(hp_##F0[3]);

#define ACC8(WW, V)                                                         \
    {                                                                       \
        DEC8(V, f0, f1, f2, f3)                                             \
        a0 = fmaf((WW), f0.x, a0); a1 = fmaf((WW), f0.y, a1);               \
        a2 = fmaf((WW), f1.x, a2); a3 = fmaf((WW), f1.y, a3);               \
        a4 = fmaf((WW), f2.x, a4); a5 = fmaf((WW), f2.y, a5);               \
        a6 = fmaf((WW), f3.x, a6); a7 = fmaf((WW), f3.y, a7);               \
    }

#define WDEC(Q) __half2float(__ushort_as_half((unsigned short)((Q) >> 17)))

// edge loop: unroll x8, x4, singles; packed 4B er via nt loads (all 5 lanes of a
// node hit the same address -> one 4B request/edge)
#define EDGE_LOOP                                                           \
    int e = beg;                                                            \
    int e8 = beg + ((end - beg) & ~7);                                      \
    for (; e < e8; e += 8) {                                                \
        unsigned q0 = __builtin_nontemporal_load(er + e);                   \
        unsigned q1 = __builtin_nontemporal_load(er + e + 1);               \
        unsigned q2 = __builtin_nontemporal_load(er + e + 2);               \
        unsigned q3 = __builtin_nontemporal_load(er + e + 3);               \
        unsigned q4 = __builtin_nontemporal_load(er + e + 4);               \
        unsigned q5 = __builtin_nontemporal_load(er + e + 5);               \
        unsigned q6 = __builtin_nontemporal_load(er + e + 6);               \
        unsigned q7 = __builtin_nontemporal_load(er + e + 7);               \
        float4 v0 = x[(q0 & 0x1FFFFu) * m + a];                             \
        float4 v1 = x[(q1 & 0x1FFFFu) * m + a];                             \
        float4 v2 = x[(q2 & 0x1FFFFu) * m + a];                             \
        float4 v3 = x[(q3 & 0x1FFFFu) * m + a];                             \
        float4 v4 = x[(q4 & 0x1FFFFu) * m + a];                             \
        float4 v5 = x[(q5 & 0x1FFFFu) * m + a];                             \
        float4 v6 = x[(q6 & 0x1FFFFu) * m + a];                             \
        float4 v7 = x[(q7 & 0x1FFFFu) * m + a];                             \
        ACC8(WDEC(q0), v0); ACC8(WDEC(q1), v1);                             \
        ACC8(WDEC(q2), v2); ACC8(WDEC(q3), v3);                             \
        ACC8(WDEC(q4), v4); ACC8(WDEC(q5), v5);                             \
        ACC8(WDEC(q6), v6); ACC8(WDEC(q7), v7);                             \
    }                                                                       \
    int e4 = e + ((end - e) & ~3);                                          \
    for (; e < e4; e += 4) {                                                \
        unsigned q0 = __builtin_nontemporal_load(er + e);                   \
        unsigned q1 = __builtin_nontemporal_load(er + e + 1);               \
        unsigned q2 = __builtin_nontemporal_load(er + e + 2);               \
        unsigned q3 = __builtin_nontemporal_load(er + e + 3);               \
        float4 v0 = x[(q0 & 0x1FFFFu) * m + a];                             \
        float4 v1 = x[(q1 & 0x1FFFFu) * m + a];                             \
        float4 v2 = x[(q2 & 0x1FFFFu) * m + a];                             \
        float4 v3 = x[(q3 & 0x1FFFFu) * m + a];                             \
        ACC8(WDEC(q0), v0); ACC8(WDEC(q1), v1);                             \
        ACC8(WDEC(q2), v2); ACC8(WDEC(q3), v3);                             \
    }                                                                       \
    for (; e < end; ++e) {                                                  \
        unsigned q = __builtin_nontemporal_load(er + e);                    \
        float4 v = x[(q & 0x1FFFFu) * m + a];                               \
        ACC8(WDEC(q), v);                                                   \
    }

// lane -> (node g, sub-lane li, stride m, plane offset a); 2 waves/block,
// 12 nodes/wave (5 lanes each; lanes 60-63 of each wave idle)
#define LANE_SETUP                                                          \
    int wv = threadIdx.x >> 6;                                              \
    int lane = threadIdx.x & 63;                                            \
    int nw = lane / 5;                                                      \
    int li = lane - nw * 5;                                                 \
    int g = blockIdx.x * 24 + wv * 12 + nw;                                 \
    if (nw >= 12 || g >= NN) return;                                        \
    int m = (li < 4) ? 4 : 1;                                               \
    int a = (li < 4) ? li : PL1;

// ---------- SpMM propagate: x_out = A_hat * x (fp16, dual-plane) ----------
__global__ __launch_bounds__(128) void spmm_prop(
    const float4* __restrict__ x, float4* __restrict__ x_out,
    const int* __restrict__ row_ptr, const unsigned int* __restrict__ er,
    const float* __restrict__ dinv) {
    LANE_SETUP
    int beg = row_ptr[g], end = row_ptr[g + 1];
    float di = dinv[g];
    float w0 = di * di;
    int base = g * m + a;
    float4 sv = x[base];
    float a0, a1, a2, a3, a4, a5, a6, a7;
    {
        DEC8(sv, f0, f1, f2, f3)
        a0 = w0 * f0.x; a1 = w0 * f0.y; a2 = w0 * f1.x; a3 = w0 * f1.y;
        a4 = w0 * f2.x; a5 = w0 * f2.y; a6 = w0 * f3.x; a7 = w0 * f3.y;
    }
    EDGE_LOOP
    float4 ov;
    __half2* op = (__half2*)&ov;
    op[0] = __floats2half2_rn(a0, a1);
    op[1] = __floats2half2_rn(a2, a3);
    op[2] = __floats2half2_rn(a4, a5);
    op[3] = __floats2half2_rn(a6, a7);
    __builtin_nontemporal_store(*(const vf4*)&ov, (vf4*)(x_out + base));
}

// ---------- final: acc = A*x15 (=x16); out = C16*x16 + C15*x15 + C14*x14
//            + C13*x13 + FC*y0 + bias   (k<=12 terms <= ~3e-6, dropped)
__global__ __launch_bounds__(128) void spmm_final(
    const float4* __restrict__ x,     // x15 (gather source)
    const float4* __restrict__ x13p,
    const float4* __restrict__ x14p,
    const float4* __restrict__ y0,
    const float* __restrict__ bias,
    const int* __restrict__ row_ptr, const unsigned int* __restrict__ er,
    const float* __restrict__ dinv, float* __restrict__ outp) {
    LANE_SETUP
    int beg = row_ptr[g], end = row_ptr[g + 1];
    float di = dinv[g];
    float w0 = di * di;
    int base = g * m + a;
    float4 sv = x[base];
    float s0, s1, s2, s3, s4, s5, s6, s7;
    float a0, a1, a2, a3, a4, a5, a6, a7;
    {
        DEC8(sv, f0, f1, f2, f3)
        s0 = f0.x; s1 = f0.y; s2 = f1.x; s3 = f1.y;
        s4 = f2.x; s5 = f2.y; s6 = f3.x; s7 = f3.y;
        a0 = w0 * s0; a1 = w0 * s1; a2 = w0 * s2; a3 = w0 * s3;
        a4 = w0 * s4; a5 = w0 * s5; a6 = w0 * s6; a7 = w0 * s7;
    }
    EDGE_LOOP
    const float C16 = 0.95f / 16.0f;
    const float C15 = 0.95f / 256.0f;
    const float C14 = 0.95f / 4096.0f;
    const float C13 = 0.95f / 65536.0f;
    const float FC  = 0.05f / 15.0f;
    float o0 = C16 * a0 + C15 * s0, o1 = C16 * a1 + C15 * s1;
    float o2 = C16 * a2 + C15 * s2, o3 = C16 * a3 + C15 * s3;
    float o4 = C16 * a4 + C15 * s4, o5 = C16 * a5 + C15 * s5;
    float o6 = C16 * a6 + C15 * s6, o7 = C16 * a7 + C15 * s7;
#define ADD8(P, CF)                                                         \
    {                                                                       \
        float4 v = (P)[base];                                               \
        DEC8(v, f0, f1, f2, f3)                                             \
        o0 = fmaf((CF), f0.x, o0); o1 = fmaf((CF), f0.y, o1);               \
        o2 = fmaf((CF), f1.x, o2); o3 = fmaf((CF), f1.y, o3);               \
        o4 = fmaf((CF), f2.x, o4); o5 = fmaf((CF), f2.y, o5);               \
        o6 = fmaf((CF), f3.x, o6); o7 = fmaf((CF), f3.y, o7);               \
    }
    ADD8(x14p, C14)
    ADD8(x13p, C13)
    ADD8(y0, FC)
#undef ADD8
    const float4* b4 = (const float4*)(bias + li * 8);
    float4 bb0 = b4[0], bb1 = b4[1];
    vf4 w0v = {o0 + bb0.x, o1 + bb0.y, o2 + bb0.z, o3 + bb0.w};
    vf4 w1v = {o4 + bb1.x, o5 + bb1.y, o6 + bb1.z, o7 + bb1.w};
    vf4* op = (vf4*)(outp + (size_t)g * CC + li * 8);
    __builtin_nontemporal_store(w0v, op);
    __builtin_nontemporal_store(w1v, op + 1);
}

extern "C" void kernel_launch(void* const* d_in, const int* in_sizes, int n_in,
                              void* d_out, int out_size, void* d_ws, size_t ws_size,
                              hipStream_t stream) {
    const float* feat = (const float*)d_in[0];
    const float* W    = (const float*)d_in[1];
    const float* b    = (const float*)d_in[2];
    const int*   src  = (const int*)d_in[3];
    const int*   dst  = (const int*)d_in[4];
    float* out = (float*)d_out;

    char* p = (char*)d_ws;
    auto alloc = [&](size_t bytes) {
        char* r = p;
        p += (bytes + 255) & ~(size_t)255;
        return r;
    };
    float*        dinv    = (float*)alloc((size_t)NN * sizeof(float));
    int*          row_ptr = (int*)alloc((size_t)(NN + 1) * sizeof(int));
    int*          cursor  = (int*)alloc((size_t)NBK * sizeof(int));
    int*          bbase   = (int*)alloc((size_t)NBK * sizeof(int));
    int2*         tmp     = (int2*)alloc((size_t)NBK * TCAP * sizeof(int2)); // 12.6MB
    int2*         er2     = (int2*)alloc((size_t)EE * sizeof(int2));         // 9.6MB
    unsigned int* er4     = (unsigned int*)alloc((size_t)EE * sizeof(int));  // 4.8MB
    float4*       y0      = (float4*)alloc((size_t)NN * 5 * sizeof(float4)); // 8MB
    float4*       xa      = (float4*)alloc((size_t)NN * 5 * sizeof(float4)); // 8MB
    float4*       xb      = (float4*)alloc((size_t)NN * 5 * sizeof(float4)); // 8MB
    float4*       x13b    = (float4*)alloc((size_t)NN * 5 * sizeof(float4)); // 8MB
    float4*       x14b    = (float4*)alloc((size_t)NN * 5 * sizeof(float4)); // 8MB
    float4*       x15b    = (float4*)alloc((size_t)NN * 5 * sizeof(float4)); // 8MB

    curinit_kernel<<<1, 512, 0, stream>>>(cursor);
    sortA_kernel<<<ABLK, 256, 0, stream>>>(src, dst, cursor, tmp);
    bscan_kernel<<<1, 512, 0, stream>>>(cursor, bbase, row_ptr);
    sortB_kernel<<<NBK, 256, 0, stream>>>(tmp, cursor, bbase, dinv, row_ptr, er2);
    wfill_kernel<<<(EE + 255) / 256, 256, 0, stream>>>(er2, dinv, er4);
    proj_kernel<<<(NN + 63) / 64, 256, 0, stream>>>((const float4*)feat, W, y0);

    // j = 0..11: ping-pong xa/xb (x1..x12 don't feed the output)
    const float4* xs = y0;
    for (int j = 0; j < 12; ++j) {
        float4* xd = (j & 1) ? xb : xa;
        spmm_prop<<<GBLK24, 128, 0, stream>>>(xs, xd, row_ptr, er4, dinv);
        xs = xd;
    }
    // x13, x14, x15 into preserved buffers
    spmm_prop<<<GBLK24, 128, 0, stream>>>(xs, x13b, row_ptr, er4, dinv);
    spmm_prop<<<GBLK24, 128, 0, stream>>>(x13b, x14b, row_ptr, er4, dinv);
    spmm_prop<<<GBLK24, 128, 0, stream>>>(x14b, x15b, row_ptr, er4, dinv);
    // final: acc = A*x15 (=x16), combine x16,x15,x14,x13,y0,bias -> out
    spmm_final<<<GBLK24, 128, 0, stream>>>(x15b, x13b, x14b, y0, b, row_ptr,
                                           er4, dinv, out);
}